// Round 19
// baseline (220.579 us; speedup 1.0000x reference)
//
#include <hip/hip_runtime.h>
#include <math.h>

typedef unsigned short u16;
typedef unsigned char u8;
typedef __bf16 bf16x8 __attribute__((ext_vector_type(8)));
typedef float f32x4 __attribute__((ext_vector_type(4)));

__device__ __forceinline__ u16 f2bf(float f){
  union{float f; unsigned u;} v; v.f = f;
  return (u16)((v.u + 0x7fffu + ((v.u >> 16) & 1u)) >> 16);
}
__device__ __forceinline__ u8 f2fp8(float f){
  return (u8)(__builtin_amdgcn_cvt_pk_fp8_f32(f, f, 0, false) & 0xff);
}

#define LOG2E 1.4426950408889634f

// ---------------------------------------------------------------------------
// Mega-prep: one dispatch, four independent jobs branch on blockIdx.
__global__ __launch_bounds__(256) void prep_all(
    const float* __restrict__ sp, const float* __restrict__ ed,
    const float* __restrict__ Wq, const float* __restrict__ Wk,
    const float* __restrict__ Wv, const float* __restrict__ Wo,
    const float* __restrict__ W1, const float* __restrict__ W2,
    const float* __restrict__ g1, const float* __restrict__ g2,
    const float* __restrict__ be1, const float* __restrict__ be2,
    const float* __restrict__ bv, const float* __restrict__ bf1,
    const float* __restrict__ bo, const float* __restrict__ bf2,
    const float* __restrict__ x,
    u16* __restrict__ biasPb, u16* __restrict__ WqkvT, u16* __restrict__ WoT,
    u16* __restrict__ W1T, u8* __restrict__ W2T8,
    float* __restrict__ qkvb, float* __restrict__ bf1f, float* __restrict__ bo2,
    u16* __restrict__ hn, float qscale){
  __shared__ float t[32][33];
  __shared__ float red[4][64];
  const int gbid = blockIdx.x, tid = threadIdx.x;

  if (gbid < 4096){
    // ---- bias_prep ----
    int tt = gbid * 256 + tid;
    int row = tt >> 7, c0 = (tt & 127) * 4;
    size_t base = (size_t)row * 512;
    float4 s = *(const float4*)&sp[base + c0];
    float4 e = *(const float4*)&ed[base + c0];
    int kt = c0 >> 7, cw = c0 & 127, fk = cw >> 4, l0 = cw & 15;
    u16* o = biasPb + base + kt*128 + fk;
    o[(l0+0)*8] = f2bf((s.x+e.x)*LOG2E);
    o[(l0+1)*8] = f2bf((s.y+e.y)*LOG2E);
    o[(l0+2)*8] = f2bf((s.z+e.z)*LOG2E);
    o[(l0+3)*8] = f2bf((s.w+e.w)*LOG2E);
  } else if (gbid < 11008){
    // ---- prep_weights ----
    int bid = gbid - 4096;
    const float* src; u16* dst; const float* rs; float sc; int C, bx, by; bool w2 = false;
    if (bid < 576)      {            src=Wq; dst=WqkvT;          rs=g1;      sc=qscale; C=768;  bx=bid%24; by=bid/24; }
    else if (bid <1152) { bid-=576;  src=Wk; dst=WqkvT+768*768;  rs=g1;      sc=1.f;    C=768;  bx=bid%24; by=bid/24; }
    else if (bid <1728) { bid-=1152; src=Wv; dst=WqkvT+1536*768; rs=g1;      sc=1.f;    C=768;  bx=bid%24; by=bid/24; }
    else if (bid <2304) { bid-=1728; src=Wo; dst=WoT;            rs=nullptr; sc=1.f;    C=768;  bx=bid%24; by=bid/24; }
    else if (bid <4608) { bid-=2304; src=W1; dst=W1T;            rs=g2;      sc=1.f;    C=3072; bx=bid%96; by=bid/96; }
    else                { bid-=4608; src=W2; dst=nullptr;        rs=nullptr; sc=1.f;    C=768;  bx=bid%24; by=bid/24; w2 = true; }
    int c0 = bx * 32, r0 = by * 32;
    int tx = tid & 31, ty = tid >> 5;
    #pragma unroll
    for (int i = 0; i < 4; i++)
      t[ty + i*8][tx] = src[(size_t)(r0 + ty + i*8) * C + c0 + tx];
    __syncthreads();
    if (w2){
      // W2T8[n][k] = fp8(W2[k][n]), K-tile-local chunk swizzle c8 ^= n&7
      #pragma unroll
      for (int i = 0; i < 4; i++){
        int n = c0 + ty + i*8, k = r0 + tx;
        size_t a = (size_t)n*3072 + (k & ~63) + ((((k>>3)&7) ^ (n&7)) << 3) + (k&7);
        W2T8[a] = f2fp8(t[tx][ty + i*8]);
      }
    } else {
      float fac = (rs ? rs[r0 + tx] : 1.f) * sc;
      #pragma unroll
      for (int i = 0; i < 4; i++)
        dst[(size_t)(c0 + ty + i*8) * 768 + r0 + tx] = f2bf(t[tx][ty + i*8] * fac);
    }
  } else if (gbid < 11104){
    // ---- fold_bias ----
    int fbid = gbid - 11008;
    int tx = tid & 63, ty = tid >> 6;
    int j = fbid * 64 + tx;                  // 0..6143
    if (j < 5376){
      const float* W; int col, stride; const float* bvec;
      if (j < 768)       { W = Wq; col = j;        stride = 768;  bvec = be1; }
      else if (j < 1536) { W = Wk; col = j - 768;  stride = 768;  bvec = be1; }
      else if (j < 2304) { W = Wv; col = j - 1536; stride = 768;  bvec = be1; }
      else               { W = W1; col = j - 2304; stride = 3072; bvec = be2; }
      float s = 0.f;
      for (int k = ty * 192; k < (ty + 1) * 192; k++)
        s += bvec[k] * W[(size_t)k * stride + col];
      red[ty][tx] = s;
    }
    __syncthreads();
    if (ty == 0){
      if (j < 5376){
        float s = red[0][tx] + red[1][tx] + red[2][tx] + red[3][tx];
        if (j < 1536)      qkvb[j] = s;
        else if (j < 2304) qkvb[j] = s + bv[j - 1536];
        else               bf1f[j - 2304] = s + bf1[j - 2304];
      } else {
        int col = j - 5376;
        bo2[col] = bo[col] + bf2[col];
      }
    }
  } else {
    // ---- ln ----
    int lbid = gbid - 11104;
    const int lane = tid & 63, wave = tid >> 6;
    const int row = lbid * 4 + wave;
    const float4* xr = (const float4*)(x + (size_t)row * 768);
    float4 v[3];
    float sum = 0.f, sq = 0.f;
    #pragma unroll
    for (int c = 0; c < 3; c++){
      v[c] = xr[lane + 64*c];
      sum += v[c].x + v[c].y + v[c].z + v[c].w;
      sq  += v[c].x*v[c].x + v[c].y*v[c].y + v[c].z*v[c].z + v[c].w*v[c].w;
    }
    #pragma unroll
    for (int d = 1; d < 64; d <<= 1){ sum += __shfl_xor(sum, d); sq += __shfl_xor(sq, d); }
    float mu  = sum * (1.f/768.f);
    float var = sq * (1.f/768.f) - mu*mu;
    float rs  = rsqrtf(var + 1e-5f);
    #pragma unroll
    for (int c = 0; c < 3; c++){
      int f4 = lane + 64*c;
      ushort4 o{f2bf((v[c].x-mu)*rs), f2bf((v[c].y-mu)*rs),
                f2bf((v[c].z-mu)*rs), f2bf((v[c].w-mu)*rs)};
      ((ushort4*)(hn + (size_t)row*768))[f4] = o;
    }
  }
}

// ---------------------------------------------------------------------------
// qkv GEMM (proven R4 structure): C[8192,2304] = hn @ WqkvT^T + qkvb.
__global__ __launch_bounds__(256, 2) void gemm_qkv(
    const u16* __restrict__ A, const u16* __restrict__ Bt, u16* __restrict__ Cout,
    const float* __restrict__ bias, u16* __restrict__ vt){
  const int Nn = 2304, K = 768;
  __shared__ __align__(16) u16 As[128*64];
  __shared__ __align__(16) u16 Bs[128*64];
  const int tid = threadIdx.x, lane = tid & 63, wave = tid >> 6;
  const int wm = wave >> 1, wn = wave & 1;
  const int l15 = lane & 15, lg = lane >> 4;
  const int bid = blockIdx.y * gridDim.x + blockIdx.x;
  const int cpx = (gridDim.x * gridDim.y) >> 3;
  const int swz = (bid & 7) * cpx + (bid >> 3);
  const int m0 = (swz / gridDim.x) * 128, n0 = (swz % gridDim.x) * 128;
  f32x4 acc[4][4] = {};
  for (int k0 = 0; k0 < K; k0 += 64){
    #pragma unroll
    for (int i = 0; i < 4; i++){
      int chunk = i*256 + tid;
      int row = chunk >> 3, seg = (chunk & 7) ^ (row & 7);
      __builtin_amdgcn_global_load_lds(
        (const __attribute__((address_space(1))) void*)&A[(size_t)(m0+row)*K + k0 + seg*8],
        (__attribute__((address_space(3))) void*)&As[(size_t)(i*256 + wave*64)*8], 16, 0, 0);
      __builtin_amdgcn_global_load_lds(
        (const __attribute__((address_space(1))) void*)&Bt[(size_t)(n0+row)*K + k0 + seg*8],
        (__attribute__((address_space(3))) void*)&Bs[(size_t)(i*256 + wave*64)*8], 16, 0, 0);
    }
    __syncthreads();
    bf16x8 af[4][2], bfr[4][2];
    #pragma unroll
    for (int i = 0; i < 4; i++){
      int ra = wm*64 + i*16 + l15, rb = wn*64 + i*16 + l15;
      #pragma unroll
      for (int kk = 0; kk < 2; kk++){
        af[i][kk]  = *(const bf16x8*)&As[ra*64 + (((kk*4 + lg) ^ (l15 & 7)) << 3)];
        bfr[i][kk] = *(const bf16x8*)&Bs[rb*64 + (((kk*4 + lg) ^ (l15 & 7)) << 3)];
      }
    }
    #pragma unroll
    for (int kk = 0; kk < 2; kk++)
      #pragma unroll
      for (int i = 0; i < 4; i++)
        #pragma unroll
        for (int j = 0; j < 4; j++)
          acc[i][j] = __builtin_amdgcn_mfma_f32_16x16x32_bf16(af[i][kk], bfr[j][kk], acc[i][j], 0, 0, 0);
    __syncthreads();
  }
  #pragma unroll
  for (int i = 0; i < 4; i++){
    int row_base = m0 + wm*64 + i*16 + lg*4;
    #pragma unroll
    for (int j = 0; j < 4; j++){
      int col = n0 + wn*64 + j*16 + l15;
      float bcol = bias[col];
      if (col >= 1536){
        int hv = (col - 1536) >> 6, hd = (col - 1536) & 63;
        int b = row_base >> 9, n = row_base & 511;
        int within = n & 127;
        int newn = (n & ~127) + ((((within >> 3) ^ (hd & 7)) << 3)) + (within & 7);
        ushort4 ov{f2bf(acc[i][j][0] + bcol), f2bf(acc[i][j][1] + bcol),
                   f2bf(acc[i][j][2] + bcol), f2bf(acc[i][j][3] + bcol)};
        *(ushort4*)&vt[(((size_t)(b*12 + hv)*64 + hd) << 9) + newn] = ov;
      } else {
        #pragma unroll
        for (int r = 0; r < 4; r++)
          Cout[(size_t)(row_base + r) * Nn + col] = f2bf(acc[i][j][r] + bcol);
      }
    }
  }
}

// ---------------------------------------------------------------------------
// Attention body (physical id t: t%8 == XCD). P-roundtrip split per fm-half:
// Pl shrinks 34.8KB -> 17KB so the fused kernel fits 3 blocks/CU (+50% TLP).
__device__ __forceinline__ void attn_body(
    int t, u16* sm, const u16* __restrict__ qkv, const u16* __restrict__ VTg,
    const u16* __restrict__ biasPb, u16* __restrict__ Og){
  u16* Ks = sm;               // [128*64]  8192 u16
  u16* Vs = sm + 8192;        // [64*128]  8192 u16
  u16* Pl = sm + 16384;       // [4][16*136] 8704 u16
  const int tid = threadIdx.x, lane = tid & 63, wave = tid >> 6;
  const int l15 = lane & 15, lg = lane >> 4;
  const int swz = (t & 7) * 96 + (t >> 3);
  const int bh = swz >> 2, b = bh / 12, h = bh % 12;
  const int q0 = (swz & 3) * 128 + wave * 32;
  const u16* Qb = qkv + (size_t)b * 512 * 2304 + h * 64;   // row stride 2304
  const u16* Kb = Qb + 768;
  const u16* Vbh = VTg + (size_t)bh * 64 * 512;
  u16* Pw = &Pl[wave * 16 * 136];

  bf16x8 qf[2][2];
  #pragma unroll
  for (int fm = 0; fm < 2; fm++)
    #pragma unroll
    for (int kk = 0; kk < 2; kk++)
      qf[fm][kk] = *(const bf16x8*)&Qb[(size_t)(q0 + fm*16 + l15)*2304 + kk*32 + lg*8];

  f32x4 O[2][4] = {};
  float lrow[2][4] = {};

  for (int kt = 0; kt < 4; kt++){
    const int k0 = kt * 128;
    bf16x8 bb[2][4];
    #pragma unroll
    for (int fm = 0; fm < 2; fm++)
      #pragma unroll
      for (int r = 0; r < 4; r++){
        int qrow = q0 + fm*16 + lg*4 + r;
        bb[fm][r] = *(const bf16x8*)&biasPb[((size_t)(b*512 + qrow)*4 + kt)*128 + l15*8];
      }
    #pragma unroll
    for (int i = 0; i < 4; i++){
      int chunk = i*256 + tid;
      int r = chunk >> 3, cc = chunk & 7;
      __builtin_amdgcn_global_load_lds(
        (const __attribute__((address_space(1))) void*)&Kb[(size_t)(k0 + r)*2304 + ((cc ^ (r & 7)) << 3)],
        (__attribute__((address_space(3))) void*)&Ks[(size_t)(i*256 + wave*64)*8],
        16, 0, 0);
    }
    #pragma unroll
    for (int i = 0; i < 4; i++){
      int chunk = i*256 + tid;
      int r = chunk >> 4, cc = chunk & 15;
      __builtin_amdgcn_global_load_lds(
        (const __attribute__((address_space(1))) void*)&Vbh[(size_t)r*512 + k0 + (cc << 3)],
        (__attribute__((address_space(3))) void*)&Vs[(size_t)(i*256 + wave*64)*8],
        16, 0, 0);
    }
    __syncthreads();

    f32x4 S[2][8] = {};
    __builtin_amdgcn_s_setprio(1);
    #pragma unroll
    for (int fk = 0; fk < 8; fk++)
      #pragma unroll
      for (int kk = 0; kk < 2; kk++){
        int row = fk*16 + l15;
        bf16x8 kf = *(const bf16x8*)&Ks[row*64 + (((kk*4 + lg) ^ (l15 & 7)) << 3)];
        S[0][fk] = __builtin_amdgcn_mfma_f32_16x16x32_bf16(qf[0][kk], kf, S[0][fk], 0,0,0);
        S[1][fk] = __builtin_amdgcn_mfma_f32_16x16x32_bf16(qf[1][kk], kf, S[1][fk], 0,0,0);
      }
    __builtin_amdgcn_s_setprio(0);
    #pragma unroll
    for (int fm = 0; fm < 2; fm++)
      #pragma unroll
      for (int r = 0; r < 4; r++){
        float rs = 0.f;
        #pragma unroll
        for (int fk = 0; fk < 8; fk++){
          float p = exp2f(S[fm][fk][r] + (float)bb[fm][r][fk]);
          S[fm][fk][r] = p;
          rs += p;
        }
        rs += __shfl_xor(rs, 1); rs += __shfl_xor(rs, 2);
        rs += __shfl_xor(rs, 4); rs += __shfl_xor(rs, 8);
        lrow[fm][r] += rs;
      }
    // P roundtrip + PV, per fm-half (per-wave private; intra-wave ordering)
    #pragma unroll
    for (int fm = 0; fm < 2; fm++){
      #pragma unroll
      for (int fk = 0; fk < 8; fk++)
        #pragma unroll
        for (int r = 0; r < 4; r++)
          Pw[(lg*4 + r)*136 + fk*16 + l15] = f2bf(S[fm][fk][r]);
      bf16x8 pf[4];
      #pragma unroll
      for (int kk = 0; kk < 4; kk++)
        pf[kk] = *(const bf16x8*)&Pw[l15*136 + kk*32 + lg*8];
      __builtin_amdgcn_s_setprio(1);
      #pragma unroll
      for (int fn = 0; fn < 4; fn++)
        #pragma unroll
        for (int kk = 0; kk < 4; kk++){
          int row = fn*16 + l15;
          bf16x8 vf = *(const bf16x8*)&Vs[row*128 + (((kk*4 + lg) ^ (l15 & 7)) << 3)];
          O[fm][fn] = __builtin_amdgcn_mfma_f32_16x16x32_bf16(pf[kk], vf, O[fm][fn], 0,0,0);
        }
      __builtin_amdgcn_s_setprio(0);
    }
    __syncthreads();
  }
  #pragma unroll
  for (int fm = 0; fm < 2; fm++)
    #pragma unroll
    for (int r = 0; r < 4; r++){
      float inv = __builtin_amdgcn_rcpf(lrow[fm][r]);
      int qrow = q0 + fm*16 + lg*4 + r;
      #pragma unroll
      for (int fn = 0; fn < 4; fn++)
        Og[((size_t)b*512 + qrow)*768 + h*64 + fn*16 + l15] = f2bf(O[fm][fn][r] * inv);
    }
}

// ---------------------------------------------------------------------------
// FFN1 body: writes Gg8 fp8, global layout pre-swizzled (c8 ^= row&7 per 64B
// K-tile). T5 setprio around the MFMA block.
__device__ __forceinline__ void ffn1_body(
    int fid, u16* sm, const u16* __restrict__ A, const u16* __restrict__ Bt,
    u8* __restrict__ Cout, const float* __restrict__ bias){
  u16* As = sm;               // [128*64]
  u16* Bs = sm + 8192;        // [128*64]
  const int K = 768;
  const int tid = threadIdx.x, lane = tid & 63, wave = tid >> 6;
  const int wm = wave >> 1, wn = wave & 1;
  const int l15 = lane & 15, lg = lane >> 4;
  const int swz = (fid & 7) * 192 + (fid >> 3);    // nwg = 1536 (24 x 64)
  const int m0 = (swz / 24) * 128, n0 = (swz % 24) * 128;
  f32x4 acc[4][4] = {};
  for (int k0 = 0; k0 < K; k0 += 64){
    #pragma unroll
    for (int i = 0; i < 4; i++){
      int chunk = i*256 + tid;
      int row = chunk >> 3, seg = (chunk & 7) ^ (row & 7);
      __builtin_amdgcn_global_load_lds(
        (const __attribute__((address_space(1))) void*)&A[(size_t)(m0+row)*K + k0 + seg*8],
        (__attribute__((address_space(3))) void*)&As[(size_t)(i*256 + wave*64)*8], 16, 0, 0);
      __builtin_amdgcn_global_load_lds(
        (const __attribute__((address_space(1))) void*)&Bt[(size_t)(n0+row)*K + k0 + seg*8],
        (__attribute__((address_space(3))) void*)&Bs[(size_t)(i*256 + wave*64)*8], 16, 0, 0);
    }
    __syncthreads();
    bf16x8 af[4][2], bfr[4][2];
    #pragma unroll
    for (int i = 0; i < 4; i++){
      int ra = wm*64 + i*16 + l15, rb = wn*64 + i*16 + l15;
      #pragma unroll
      for (int kk = 0; kk < 2; kk++){
        af[i][kk]  = *(const bf16x8*)&As[ra*64 + (((kk*4 + lg) ^ (l15 & 7)) << 3)];
        bfr[i][kk] = *(const bf16x8*)&Bs[rb*64 + (((kk*4 + lg) ^ (l15 & 7)) << 3)];
      }
    }
    __builtin_amdgcn_s_setprio(1);
    #pragma unroll
    for (int kk = 0; kk < 2; kk++)
      #pragma unroll
      for (int i = 0; i < 4; i++)
        #pragma unroll
        for (int j = 0; j < 4; j++)
          acc[i][j] = __builtin_amdgcn_mfma_f32_16x16x32_bf16(af[i][kk], bfr[j][kk], acc[i][j], 0, 0, 0);
    __builtin_amdgcn_s_setprio(0);
    __syncthreads();
  }
  #pragma unroll
  for (int i = 0; i < 4; i++){
    int row_base = m0 + wm*64 + i*16 + lg*4;
    #pragma unroll
    for (int j = 0; j < 4; j++){
      int col = n0 + wn*64 + j*16 + l15;
      float bcol = bias[col];
      int cbase = col & ~63, c8 = (col >> 3) & 7, c7 = col & 7;
      #pragma unroll
      for (int r = 0; r < 4; r++){
        int row = row_base + r;
        float v = acc[i][j][r] + bcol;
        float u = v + 0.044715f * v * v * v;
        float e = exp2f(-2.3022182f * u);            // exp(-1.5957691*u)
        float g = v * __builtin_amdgcn_rcpf(1.f + e);
        Cout[(size_t)row*3072 + cbase + ((c8 ^ (row & 7)) << 3) + c7] = f2fp8(g);
      }
    }
  }
}

// ---------------------------------------------------------------------------
// Fused attention + FFN1: range partition (attn: 0..767, ffn1: 768..2303).
// 49KB LDS -> 3 blocks/CU (12 waves/CU).
__global__ __launch_bounds__(256, 3) void attn_ffn1(
    const u16* __restrict__ qkv, const u16* __restrict__ VTg,
    const u16* __restrict__ biasPb, u16* __restrict__ Og,
    const u16* __restrict__ hn, const u16* __restrict__ W1T,
    u8* __restrict__ Gg8, const float* __restrict__ bf1f){
  __shared__ __align__(16) u16 sm[25088];   // attn: 49KB; gemm uses first 32KB
  const int bid = blockIdx.x;
  if (bid < 768) attn_body(bid, sm, qkv, VTg, biasPb, Og);
  else           ffn1_body(bid - 768, sm, hn, W1T, Gg8, bf1f);
}

// ---------------------------------------------------------------------------
// Final GEMM, concatenated K: d_out = Gg8(fp8)@W2T8(fp8) [K 0..3072 bytes]
//   + Og(bf16)@WoT(bf16) [K 768] + bo2 + x.  f32 out.
__global__ __launch_bounds__(256, 2) void gemm_fin(
    const u8* __restrict__ Gg8, const u16* __restrict__ Og,
    const u8* __restrict__ W2T8, const u16* __restrict__ WoT,
    float* __restrict__ Cout, const float* __restrict__ bo2,
    const float* __restrict__ x){
  const int Nn = 768;
  __shared__ __align__(16) u16 As[128*64];
  __shared__ __align__(16) u16 Bs[128*64];
  u8* As8 = (u8*)As;
  u8* Bs8 = (u8*)Bs;
  const int tid = threadIdx.x, lane = tid & 63, wave = tid >> 6;
  const int wm = wave >> 1, wn = wave & 1;
  const int l15 = lane & 15, lg = lane >> 4;
  const int bid = blockIdx.y * gridDim.x + blockIdx.x;
  const int cpx = (gridDim.x * gridDim.y) >> 3;
  const int swz = (bid & 7) * cpx + (bid >> 3);
  const int m0 = (swz / gridDim.x) * 128, n0 = (swz % gridDim.x) * 128;
  f32x4 acc[4][4] = {};

  // --- fp8 section: Gg8 @ W2T8, K = 3072 bytes, BK = 64 ---
  for (int k0 = 0; k0 < 3072; k0 += 64){
    #pragma unroll
    for (int i = 0; i < 2; i++){
      int chunk = i*256 + tid;
      int row = chunk >> 2, c16 = chunk & 3;
      __builtin_amdgcn_global_load_lds(
        (const __attribute__((address_space(1))) void*)&Gg8[(size_t)(m0+row)*3072 + k0 + c16*16],
        (__attribute__((address_space(3))) void*)&As8[(size_t)(i*256 + wave*64)*16], 16, 0, 0);
      __builtin_amdgcn_global_load_lds(
        (const __attribute__((address_space(1))) void*)&W2T8[(size_t)(n0+row)*3072 + k0 + c16*16],
        (__attribute__((address_space(3))) void*)&Bs8[(size_t)(i*256 + wave*64)*16], 16, 0, 0);
    }
    __syncthreads();
    long a8[4][2], b8[4][2];
    #pragma unroll
    for (int i = 0; i < 4; i++){
      int ra = wm*64 + i*16 + l15, rb = wn*64 + i*16 + l15;
      #pragma unroll
      for (int kk = 0; kk < 2; kk++){
        a8[i][kk] = *(const long*)&As8[ra*64 + (((kk*4 + lg) ^ (l15 & 7)) << 3)];
        b8[i][kk] = *(const long*)&Bs8[rb*64 + (((kk*4 + lg) ^ (l15 & 7)) << 3)];
      }
    }
    #pragma unroll
    for (int kk = 0; kk < 2; kk++)
      #pragma unroll
      for (int i = 0; i < 4; i++)
        #pragma unroll
        for (int j = 0; j < 4; j++)
          acc[i][j] = __builtin_amdgcn_mfma_f32_16x16x32_fp8_fp8(a8[i][kk], b8[j][kk], acc[i][j], 0, 0, 0);
    __syncthreads();
  }

  // --- bf16 section: Og @ WoT, K = 768 ---
  for (int k0 = 0; k0 < 768; k0 += 64){
    #pragma unroll
    for (int i = 0; i < 4; i++){
      int chunk = i*256 + tid;
      int row = chunk >> 3, seg = (chunk & 7) ^ (row & 7);
      __builtin_amdgcn_global_load_lds(
        (const __attribute__((address_space(1))) void*)&Og[(size_t)(m0+row)*768 + k0 + seg*8],
        (__attribute__((address_space(3))) void*)&As[(size_t)(i*256 + wave*64)*8], 16, 0, 0);
      __builtin_amdgcn_global_load_lds(
        (const __attribute__((address_space(1))) void*)&WoT[(size_t)(n0+row)*768 + k0 + seg*8],
        (__attribute__((address_space(3))) void*)&Bs[(size_t)(i*256 + wave*64)*8], 16, 0, 0);
    }
    __syncthreads();
    bf16x8 af[4][2], bfr[4][2];
    #pragma unroll
    for (int i = 0; i < 4; i++){
      int ra = wm*64 + i*16 + l15, rb = wn*64 + i*16 + l15;
      #pragma unroll
      for (int kk = 0; kk < 2; kk++){
        af[i][kk]  = *(const bf16x8*)&As[ra*64 + (((kk*4 + lg) ^ (l15 & 7)) << 3)];
        bfr[i][kk] = *(const bf16x8*)&Bs[rb*64 + (((kk*4 + lg) ^ (l15 & 7)) << 3)];
      }
    }
    #pragma unroll
    for (int kk = 0; kk < 2; kk++)
      #pragma unroll
      for (int i = 0; i < 4; i++)
        #pragma unroll
        for (int j = 0; j < 4; j++)
          acc[i][j] = __builtin_amdgcn_mfma_f32_16x16x32_bf16(af[i][kk], bfr[j][kk], acc[i][j], 0, 0, 0);
    __syncthreads();
  }

  #pragma unroll
  for (int i = 0; i < 4; i++){
    int row_base = m0 + wm*64 + i*16 + lg*4;
    #pragma unroll
    for (int j = 0; j < 4; j++){
      int col = n0 + wn*64 + j*16 + l15;
      float bcol = bo2[col];
      #pragma unroll
      for (int r = 0; r < 4; r++){
        size_t idx = (size_t)(row_base + r) * Nn + col;
        Cout[idx] = acc[i][j][r] + bcol + x[idx];
      }
    }
  }
}

// ---------------------------------------------------------------------------
extern "C" void kernel_launch(void* const* d_in, const int* in_sizes, int n_in,
                              void* d_out, int out_size, void* d_ws, size_t ws_size,
                              hipStream_t stream){
  const float* x   = (const float*)d_in[0];
  const float* sp  = (const float*)d_in[1];
  const float* ed  = (const float*)d_in[2];
  const float* Wq  = (const float*)d_in[3];
  const float* Wk  = (const float*)d_in[4];
  const float* Wv  = (const float*)d_in[5];
  const float* bv  = (const float*)d_in[6];
  const float* Wo  = (const float*)d_in[7];
  const float* bo  = (const float*)d_in[8];
  const float* g1  = (const float*)d_in[9];
  const float* be1 = (const float*)d_in[10];
  const float* g2  = (const float*)d_in[11];
  const float* be2 = (const float*)d_in[12];
  const float* W1  = (const float*)d_in[13];
  const float* bf1 = (const float*)d_in[14];
  const float* W2  = (const float*)d_in[15];
  const float* bf2 = (const float*)d_in[16];

  char* w = (char*)d_ws;
  size_t off = 0;
  auto alloc = [&](size_t bytes)->void*{ void* p = w + off; off += (bytes + 255) & ~(size_t)255; return p; };
  u8*    Gg8   = (u8*)   alloc(8192ull*3072);     // 25.2 MB fp8 (pre-swizzled)
  u16*   qkv   = (u16*)  alloc(8192ull*2304*2);   // 37.7 MB
  u16*   VTg   = (u16*)  alloc(8192ull*768*2);
  u16*   hn    = (u16*)  alloc(8192ull*768*2);
  u16*   Og    = (u16*)  alloc(8192ull*768*2);
  u16*   biasPb= (u16*)  alloc(16ull*512*512*2);
  u16*   WqkvT = (u16*)  alloc(2304ull*768*2);
  u16*   WoT   = (u16*)  alloc(768ull*768*2);
  u16*   W1T   = (u16*)  alloc(3072ull*768*2);
  u8*    W2T8  = (u8*)   alloc(768ull*3072);      // 2.4 MB fp8 (pre-swizzled)
  float* qkvb  = (float*)alloc(2304ull*4);
  float* bf1f  = (float*)alloc(3072ull*4);
  float* bo2   = (float*)alloc(768ull*4);

  const float qscale = 0.03608439182435161f * LOG2E;  // D^-0.5 * log2e folded into Wq

  // --- prep: 4 independent jobs, one dispatch ---
  prep_all<<<13152, 256, 0, stream>>>(sp, ed, Wq, Wk, Wv, Wo, W1, W2, g1, g2,
                                      be1, be2, bv, bf1, bo, bf2, x,
                                      biasPb, WqkvT, WoT, W1T, W2T8,
                                      qkvb, bf1f, bo2, hn, qscale);

  // --- qkv projection with fused V-transpose ---
  gemm_qkv<<<dim3(18,64),256,0,stream>>>(hn, WqkvT, qkv, qkvb, VTg);

  // --- attention + FFN1 fused (range-partitioned, 3 blocks/CU) ---
  attn_ffn1<<<2304, 256, 0, stream>>>(qkv, VTg, biasPb, Og, hn, W1T, Gg8, bf1f);

  // --- final: fp8 FFN2 + bf16 o-proj as one GEMM (+bo2 +x) ---
  gemm_fin<<<dim3(6,64),256,0,stream>>>(Gg8, Og, W2T8, WoT, (float*)d_out, bo2, x);
}

// Round 20
// 217.156 us; speedup vs baseline: 1.0158x; 1.0158x over previous
//
#include <hip/hip_runtime.h>
#include <math.h>

typedef unsigned short u16;
typedef unsigned char u8;
typedef __bf16 bf16x8 __attribute__((ext_vector_type(8)));
typedef float f32x4 __attribute__((ext_vector_type(4)));

__device__ __forceinline__ u16 f2bf(float f){
  union{float f; unsigned u;} v; v.f = f;
  return (u16)((v.u + 0x7fffu + ((v.u >> 16) & 1u)) >> 16);
}
__device__ __forceinline__ u8 f2fp8(float f){
  return (u8)(__builtin_amdgcn_cvt_pk_fp8_f32(f, f, 0, false) & 0xff);
}

#define LOG2E 1.4426950408889634f

// ---------------------------------------------------------------------------
// Mega-prep: one dispatch, four independent jobs branch on blockIdx.
__global__ __launch_bounds__(256) void prep_all(
    const float* __restrict__ sp, const float* __restrict__ ed,
    const float* __restrict__ Wq, const float* __restrict__ Wk,
    const float* __restrict__ Wv, const float* __restrict__ Wo,
    const float* __restrict__ W1, const float* __restrict__ W2,
    const float* __restrict__ g1, const float* __restrict__ g2,
    const float* __restrict__ be1, const float* __restrict__ be2,
    const float* __restrict__ bv, const float* __restrict__ bf1,
    const float* __restrict__ bo, const float* __restrict__ bf2,
    const float* __restrict__ x,
    u16* __restrict__ biasPb, u16* __restrict__ WqkvT, u16* __restrict__ WoT,
    u16* __restrict__ W1T, u8* __restrict__ W2T8,
    float* __restrict__ qkvb, float* __restrict__ bf1f, float* __restrict__ bo2,
    u16* __restrict__ hn, float qscale){
  __shared__ float t[32][33];
  __shared__ float red[4][64];
  const int gbid = blockIdx.x, tid = threadIdx.x;

  if (gbid < 4096){
    // ---- bias_prep ----
    int tt = gbid * 256 + tid;
    int row = tt >> 7, c0 = (tt & 127) * 4;
    size_t base = (size_t)row * 512;
    float4 s = *(const float4*)&sp[base + c0];
    float4 e = *(const float4*)&ed[base + c0];
    int kt = c0 >> 7, cw = c0 & 127, fk = cw >> 4, l0 = cw & 15;
    u16* o = biasPb + base + kt*128 + fk;
    o[(l0+0)*8] = f2bf((s.x+e.x)*LOG2E);
    o[(l0+1)*8] = f2bf((s.y+e.y)*LOG2E);
    o[(l0+2)*8] = f2bf((s.z+e.z)*LOG2E);
    o[(l0+3)*8] = f2bf((s.w+e.w)*LOG2E);
  } else if (gbid < 11008){
    // ---- prep_weights ----
    int bid = gbid - 4096;
    const float* src; u16* dst; const float* rs; float sc; int C, bx, by; bool w2 = false;
    if (bid < 576)      {            src=Wq; dst=WqkvT;          rs=g1;      sc=qscale; C=768;  bx=bid%24; by=bid/24; }
    else if (bid <1152) { bid-=576;  src=Wk; dst=WqkvT+768*768;  rs=g1;      sc=1.f;    C=768;  bx=bid%24; by=bid/24; }
    else if (bid <1728) { bid-=1152; src=Wv; dst=WqkvT+1536*768; rs=g1;      sc=1.f;    C=768;  bx=bid%24; by=bid/24; }
    else if (bid <2304) { bid-=1728; src=Wo; dst=WoT;            rs=nullptr; sc=1.f;    C=768;  bx=bid%24; by=bid/24; }
    else if (bid <4608) { bid-=2304; src=W1; dst=W1T;            rs=g2;      sc=1.f;    C=3072; bx=bid%96; by=bid/96; }
    else                { bid-=4608; src=W2; dst=nullptr;        rs=nullptr; sc=1.f;    C=768;  bx=bid%24; by=bid/24; w2 = true; }
    int c0 = bx * 32, r0 = by * 32;
    int tx = tid & 31, ty = tid >> 5;
    #pragma unroll
    for (int i = 0; i < 4; i++)
      t[ty + i*8][tx] = src[(size_t)(r0 + ty + i*8) * C + c0 + tx];
    __syncthreads();
    if (w2){
      // W2T8[n][k] = fp8(W2[k][n]), K-tile-local chunk swizzle c8 ^= n&7
      #pragma unroll
      for (int i = 0; i < 4; i++){
        int n = c0 + ty + i*8, k = r0 + tx;
        size_t a = (size_t)n*3072 + (k & ~63) + ((((k>>3)&7) ^ (n&7)) << 3) + (k&7);
        W2T8[a] = f2fp8(t[tx][ty + i*8]);
      }
    } else {
      float fac = (rs ? rs[r0 + tx] : 1.f) * sc;
      #pragma unroll
      for (int i = 0; i < 4; i++)
        dst[(size_t)(c0 + ty + i*8) * 768 + r0 + tx] = f2bf(t[tx][ty + i*8] * fac);
    }
  } else if (gbid < 11104){
    // ---- fold_bias ----
    int fbid = gbid - 11008;
    int tx = tid & 63, ty = tid >> 6;
    int j = fbid * 64 + tx;                  // 0..6143
    if (j < 5376){
      const float* W; int col, stride; const float* bvec;
      if (j < 768)       { W = Wq; col = j;        stride = 768;  bvec = be1; }
      else if (j < 1536) { W = Wk; col = j - 768;  stride = 768;  bvec = be1; }
      else if (j < 2304) { W = Wv; col = j - 1536; stride = 768;  bvec = be1; }
      else               { W = W1; col = j - 2304; stride = 3072; bvec = be2; }
      float s = 0.f;
      for (int k = ty * 192; k < (ty + 1) * 192; k++)
        s += bvec[k] * W[(size_t)k * stride + col];
      red[ty][tx] = s;
    }
    __syncthreads();
    if (ty == 0){
      if (j < 5376){
        float s = red[0][tx] + red[1][tx] + red[2][tx] + red[3][tx];
        if (j < 1536)      qkvb[j] = s;
        else if (j < 2304) qkvb[j] = s + bv[j - 1536];
        else               bf1f[j - 2304] = s + bf1[j - 2304];
      } else {
        int col = j - 5376;
        bo2[col] = bo[col] + bf2[col];
      }
    }
  } else {
    // ---- ln ----
    int lbid = gbid - 11104;
    const int lane = tid & 63, wave = tid >> 6;
    const int row = lbid * 4 + wave;
    const float4* xr = (const float4*)(x + (size_t)row * 768);
    float4 v[3];
    float sum = 0.f, sq = 0.f;
    #pragma unroll
    for (int c = 0; c < 3; c++){
      v[c] = xr[lane + 64*c];
      sum += v[c].x + v[c].y + v[c].z + v[c].w;
      sq  += v[c].x*v[c].x + v[c].y*v[c].y + v[c].z*v[c].z + v[c].w*v[c].w;
    }
    #pragma unroll
    for (int d = 1; d < 64; d <<= 1){ sum += __shfl_xor(sum, d); sq += __shfl_xor(sq, d); }
    float mu  = sum * (1.f/768.f);
    float var = sq * (1.f/768.f) - mu*mu;
    float rs  = rsqrtf(var + 1e-5f);
    #pragma unroll
    for (int c = 0; c < 3; c++){
      int f4 = lane + 64*c;
      ushort4 o{f2bf((v[c].x-mu)*rs), f2bf((v[c].y-mu)*rs),
                f2bf((v[c].z-mu)*rs), f2bf((v[c].w-mu)*rs)};
      ((ushort4*)(hn + (size_t)row*768))[f4] = o;
    }
  }
}

// ---------------------------------------------------------------------------
// qkv GEMM (proven R4 structure): C[8192,2304] = hn @ WqkvT^T + qkvb.
__global__ __launch_bounds__(256, 2) void gemm_qkv(
    const u16* __restrict__ A, const u16* __restrict__ Bt, u16* __restrict__ Cout,
    const float* __restrict__ bias, u16* __restrict__ vt){
  const int Nn = 2304, K = 768;
  __shared__ __align__(16) u16 As[128*64];
  __shared__ __align__(16) u16 Bs[128*64];
  const int tid = threadIdx.x, lane = tid & 63, wave = tid >> 6;
  const int wm = wave >> 1, wn = wave & 1;
  const int l15 = lane & 15, lg = lane >> 4;
  const int bid = blockIdx.y * gridDim.x + blockIdx.x;
  const int cpx = (gridDim.x * gridDim.y) >> 3;
  const int swz = (bid & 7) * cpx + (bid >> 3);
  const int m0 = (swz / gridDim.x) * 128, n0 = (swz % gridDim.x) * 128;
  f32x4 acc[4][4] = {};
  for (int k0 = 0; k0 < K; k0 += 64){
    #pragma unroll
    for (int i = 0; i < 4; i++){
      int chunk = i*256 + tid;
      int row = chunk >> 3, seg = (chunk & 7) ^ (row & 7);
      __builtin_amdgcn_global_load_lds(
        (const __attribute__((address_space(1))) void*)&A[(size_t)(m0+row)*K + k0 + seg*8],
        (__attribute__((address_space(3))) void*)&As[(size_t)(i*256 + wave*64)*8], 16, 0, 0);
      __builtin_amdgcn_global_load_lds(
        (const __attribute__((address_space(1))) void*)&Bt[(size_t)(n0+row)*K + k0 + seg*8],
        (__attribute__((address_space(3))) void*)&Bs[(size_t)(i*256 + wave*64)*8], 16, 0, 0);
    }
    __syncthreads();
    bf16x8 af[4][2], bfr[4][2];
    #pragma unroll
    for (int i = 0; i < 4; i++){
      int ra = wm*64 + i*16 + l15, rb = wn*64 + i*16 + l15;
      #pragma unroll
      for (int kk = 0; kk < 2; kk++){
        af[i][kk]  = *(const bf16x8*)&As[ra*64 + (((kk*4 + lg) ^ (l15 & 7)) << 3)];
        bfr[i][kk] = *(const bf16x8*)&Bs[rb*64 + (((kk*4 + lg) ^ (l15 & 7)) << 3)];
      }
    }
    #pragma unroll
    for (int kk = 0; kk < 2; kk++)
      #pragma unroll
      for (int i = 0; i < 4; i++)
        #pragma unroll
        for (int j = 0; j < 4; j++)
          acc[i][j] = __builtin_amdgcn_mfma_f32_16x16x32_bf16(af[i][kk], bfr[j][kk], acc[i][j], 0, 0, 0);
    __syncthreads();
  }
  #pragma unroll
  for (int i = 0; i < 4; i++){
    int row_base = m0 + wm*64 + i*16 + lg*4;
    #pragma unroll
    for (int j = 0; j < 4; j++){
      int col = n0 + wn*64 + j*16 + l15;
      float bcol = bias[col];
      if (col >= 1536){
        int hv = (col - 1536) >> 6, hd = (col - 1536) & 63;
        int b = row_base >> 9, n = row_base & 511;
        int within = n & 127;
        int newn = (n & ~127) + ((((within >> 3) ^ (hd & 7)) << 3)) + (within & 7);
        ushort4 ov{f2bf(acc[i][j][0] + bcol), f2bf(acc[i][j][1] + bcol),
                   f2bf(acc[i][j][2] + bcol), f2bf(acc[i][j][3] + bcol)};
        *(ushort4*)&vt[(((size_t)(b*12 + hv)*64 + hd) << 9) + newn] = ov;
      } else {
        #pragma unroll
        for (int r = 0; r < 4; r++)
          Cout[(size_t)(row_base + r) * Nn + col] = f2bf(acc[i][j][r] + bcol);
      }
    }
  }
}

// ---------------------------------------------------------------------------
// Attention body (physical id t: t%8 == XCD; swz groups per-XCD work).
// T5: setprio(1) around MFMA clusters (R18-verified +3us in mixed-wave kernel).
__device__ __forceinline__ void attn_body(
    int t, u16* sm, const u16* __restrict__ qkv, const u16* __restrict__ VTg,
    const u16* __restrict__ biasPb, u16* __restrict__ Og){
  u16* Ks = sm;               // [128*64]
  u16* Vs = sm + 8192;        // [64*128]
  u16* Pl = sm + 16384;       // [4*32*136]
  const int tid = threadIdx.x, lane = tid & 63, wave = tid >> 6;
  const int l15 = lane & 15, lg = lane >> 4;
  const int swz = (t & 7) * 96 + (t >> 3);
  const int bh = swz >> 2, b = bh / 12, h = bh % 12;
  const int q0 = (swz & 3) * 128 + wave * 32;
  const u16* Qb = qkv + (size_t)b * 512 * 2304 + h * 64;   // row stride 2304
  const u16* Kb = Qb + 768;
  const u16* Vbh = VTg + (size_t)bh * 64 * 512;
  u16* Pw = &Pl[wave * 32 * 136];

  bf16x8 qf[2][2];
  #pragma unroll
  for (int fm = 0; fm < 2; fm++)
    #pragma unroll
    for (int kk = 0; kk < 2; kk++)
      qf[fm][kk] = *(const bf16x8*)&Qb[(size_t)(q0 + fm*16 + l15)*2304 + kk*32 + lg*8];

  f32x4 O[2][4] = {};
  float lrow[2][4] = {};

  for (int kt = 0; kt < 4; kt++){
    const int k0 = kt * 128;
    bf16x8 bb[2][4];
    #pragma unroll
    for (int fm = 0; fm < 2; fm++)
      #pragma unroll
      for (int r = 0; r < 4; r++){
        int qrow = q0 + fm*16 + lg*4 + r;
        bb[fm][r] = *(const bf16x8*)&biasPb[((size_t)(b*512 + qrow)*4 + kt)*128 + l15*8];
      }
    #pragma unroll
    for (int i = 0; i < 4; i++){
      int chunk = i*256 + tid;
      int r = chunk >> 3, cc = chunk & 7;
      __builtin_amdgcn_global_load_lds(
        (const __attribute__((address_space(1))) void*)&Kb[(size_t)(k0 + r)*2304 + ((cc ^ (r & 7)) << 3)],
        (__attribute__((address_space(3))) void*)&Ks[(size_t)(i*256 + wave*64)*8],
        16, 0, 0);
    }
    #pragma unroll
    for (int i = 0; i < 4; i++){
      int chunk = i*256 + tid;
      int r = chunk >> 4, cc = chunk & 15;
      __builtin_amdgcn_global_load_lds(
        (const __attribute__((address_space(1))) void*)&Vbh[(size_t)r*512 + k0 + (cc << 3)],
        (__attribute__((address_space(3))) void*)&Vs[(size_t)(i*256 + wave*64)*8],
        16, 0, 0);
    }
    __syncthreads();

    f32x4 S[2][8] = {};
    __builtin_amdgcn_s_setprio(1);
    #pragma unroll
    for (int fk = 0; fk < 8; fk++)
      #pragma unroll
      for (int kk = 0; kk < 2; kk++){
        int row = fk*16 + l15;
        bf16x8 kf = *(const bf16x8*)&Ks[row*64 + (((kk*4 + lg) ^ (l15 & 7)) << 3)];
        S[0][fk] = __builtin_amdgcn_mfma_f32_16x16x32_bf16(qf[0][kk], kf, S[0][fk], 0,0,0);
        S[1][fk] = __builtin_amdgcn_mfma_f32_16x16x32_bf16(qf[1][kk], kf, S[1][fk], 0,0,0);
      }
    __builtin_amdgcn_s_setprio(0);
    #pragma unroll
    for (int fm = 0; fm < 2; fm++)
      #pragma unroll
      for (int r = 0; r < 4; r++){
        float rs = 0.f;
        #pragma unroll
        for (int fk = 0; fk < 8; fk++){
          float p = exp2f(S[fm][fk][r] + (float)bb[fm][r][fk]);
          S[fm][fk][r] = p;
          rs += p;
        }
        rs += __shfl_xor(rs, 1); rs += __shfl_xor(rs, 2);
        rs += __shfl_xor(rs, 4); rs += __shfl_xor(rs, 8);
        lrow[fm][r] += rs;
      }
    #pragma unroll
    for (int fm = 0; fm < 2; fm++)
      #pragma unroll
      for (int fk = 0; fk < 8; fk++)
        #pragma unroll
        for (int r = 0; r < 4; r++)
          Pw[(fm*16 + lg*4 + r)*136 + fk*16 + l15] = f2bf(S[fm][fk][r]);
    bf16x8 pf[2][4];
    #pragma unroll
    for (int fm = 0; fm < 2; fm++)
      #pragma unroll
      for (int kk = 0; kk < 4; kk++)
        pf[fm][kk] = *(const bf16x8*)&Pw[(fm*16 + l15)*136 + kk*32 + lg*8];
    __builtin_amdgcn_s_setprio(1);
    #pragma unroll
    for (int fn = 0; fn < 4; fn++)
      #pragma unroll
      for (int kk = 0; kk < 4; kk++){
        int row = fn*16 + l15;
        bf16x8 vf = *(const bf16x8*)&Vs[row*128 + (((kk*4 + lg) ^ (l15 & 7)) << 3)];
        O[0][fn] = __builtin_amdgcn_mfma_f32_16x16x32_bf16(pf[0][kk], vf, O[0][fn], 0,0,0);
        O[1][fn] = __builtin_amdgcn_mfma_f32_16x16x32_bf16(pf[1][kk], vf, O[1][fn], 0,0,0);
      }
    __builtin_amdgcn_s_setprio(0);
    __syncthreads();
  }
  #pragma unroll
  for (int fm = 0; fm < 2; fm++)
    #pragma unroll
    for (int r = 0; r < 4; r++){
      float inv = __builtin_amdgcn_rcpf(lrow[fm][r]);
      int qrow = q0 + fm*16 + lg*4 + r;
      #pragma unroll
      for (int fn = 0; fn < 4; fn++)
        Og[((size_t)b*512 + qrow)*768 + h*64 + fn*16 + l15] = f2bf(O[fm][fn][r] * inv);
    }
}

// ---------------------------------------------------------------------------
// FFN1 body: writes Gg8 fp8, global layout pre-swizzled (c8 ^= row&7 per 64B
// K-tile). T5 setprio around the MFMA block.
__device__ __forceinline__ void ffn1_body(
    int fid, u16* sm, const u16* __restrict__ A, const u16* __restrict__ Bt,
    u8* __restrict__ Cout, const float* __restrict__ bias){
  u16* As = sm;               // [128*64]
  u16* Bs = sm + 8192;        // [128*64]
  const int K = 768;
  const int tid = threadIdx.x, lane = tid & 63, wave = tid >> 6;
  const int wm = wave >> 1, wn = wave & 1;
  const int l15 = lane & 15, lg = lane >> 4;
  const int swz = (fid & 7) * 192 + (fid >> 3);    // nwg = 1536 (24 x 64)
  const int m0 = (swz / 24) * 128, n0 = (swz % 24) * 128;
  f32x4 acc[4][4] = {};
  for (int k0 = 0; k0 < K; k0 += 64){
    #pragma unroll
    for (int i = 0; i < 4; i++){
      int chunk = i*256 + tid;
      int row = chunk >> 3, seg = (chunk & 7) ^ (row & 7);
      __builtin_amdgcn_global_load_lds(
        (const __attribute__((address_space(1))) void*)&A[(size_t)(m0+row)*K + k0 + seg*8],
        (__attribute__((address_space(3))) void*)&As[(size_t)(i*256 + wave*64)*8], 16, 0, 0);
      __builtin_amdgcn_global_load_lds(
        (const __attribute__((address_space(1))) void*)&Bt[(size_t)(n0+row)*K + k0 + seg*8],
        (__attribute__((address_space(3))) void*)&Bs[(size_t)(i*256 + wave*64)*8], 16, 0, 0);
    }
    __syncthreads();
    bf16x8 af[4][2], bfr[4][2];
    #pragma unroll
    for (int i = 0; i < 4; i++){
      int ra = wm*64 + i*16 + l15, rb = wn*64 + i*16 + l15;
      #pragma unroll
      for (int kk = 0; kk < 2; kk++){
        af[i][kk]  = *(const bf16x8*)&As[ra*64 + (((kk*4 + lg) ^ (l15 & 7)) << 3)];
        bfr[i][kk] = *(const bf16x8*)&Bs[rb*64 + (((kk*4 + lg) ^ (l15 & 7)) << 3)];
      }
    }
    __builtin_amdgcn_s_setprio(1);
    #pragma unroll
    for (int kk = 0; kk < 2; kk++)
      #pragma unroll
      for (int i = 0; i < 4; i++)
        #pragma unroll
        for (int j = 0; j < 4; j++)
          acc[i][j] = __builtin_amdgcn_mfma_f32_16x16x32_bf16(af[i][kk], bfr[j][kk], acc[i][j], 0, 0, 0);
    __builtin_amdgcn_s_setprio(0);
    __syncthreads();
  }
  #pragma unroll
  for (int i = 0; i < 4; i++){
    int row_base = m0 + wm*64 + i*16 + lg*4;
    #pragma unroll
    for (int j = 0; j < 4; j++){
      int col = n0 + wn*64 + j*16 + l15;
      float bcol = bias[col];
      int cbase = col & ~63, c8 = (col >> 3) & 7, c7 = col & 7;
      #pragma unroll
      for (int r = 0; r < 4; r++){
        int row = row_base + r;
        float v = acc[i][j][r] + bcol;
        float u = v + 0.044715f * v * v * v;
        float e = exp2f(-2.3022182f * u);            // exp(-1.5957691*u)
        float g = v * __builtin_amdgcn_rcpf(1.f + e);
        Cout[(size_t)row*3072 + cbase + ((c8 ^ (row & 7)) << 3) + c7] = f2fp8(g);
      }
    }
  }
}

// ---------------------------------------------------------------------------
// Fused attention + FFN1: range partition (attn: 0..767, ffn1: 768..2303).
__global__ __launch_bounds__(256, 2) void attn_ffn1(
    const u16* __restrict__ qkv, const u16* __restrict__ VTg,
    const u16* __restrict__ biasPb, u16* __restrict__ Og,
    const u16* __restrict__ hn, const u16* __restrict__ W1T,
    u8* __restrict__ Gg8, const float* __restrict__ bf1f){
  __shared__ __align__(16) u16 sm[33792];   // attn: 66 KB; gemm uses first 32 KB
  const int bid = blockIdx.x;
  if (bid < 768) attn_body(bid, sm, qkv, VTg, biasPb, Og);
  else           ffn1_body(bid - 768, sm, hn, W1T, Gg8, bf1f);
}

// ---------------------------------------------------------------------------
// Final GEMM, concatenated K: d_out = Gg8(fp8)@W2T8(fp8) [K 0..3072 bytes]
//   + Og(bf16)@WoT(bf16) [K 768] + bo2 + x.  f32 out.
__global__ __launch_bounds__(256, 2) void gemm_fin(
    const u8* __restrict__ Gg8, const u16* __restrict__ Og,
    const u8* __restrict__ W2T8, const u16* __restrict__ WoT,
    float* __restrict__ Cout, const float* __restrict__ bo2,
    const float* __restrict__ x){
  const int Nn = 768;
  __shared__ __align__(16) u16 As[128*64];
  __shared__ __align__(16) u16 Bs[128*64];
  u8* As8 = (u8*)As;
  u8* Bs8 = (u8*)Bs;
  const int tid = threadIdx.x, lane = tid & 63, wave = tid >> 6;
  const int wm = wave >> 1, wn = wave & 1;
  const int l15 = lane & 15, lg = lane >> 4;
  const int bid = blockIdx.y * gridDim.x + blockIdx.x;
  const int cpx = (gridDim.x * gridDim.y) >> 3;
  const int swz = (bid & 7) * cpx + (bid >> 3);
  const int m0 = (swz / gridDim.x) * 128, n0 = (swz % gridDim.x) * 128;
  f32x4 acc[4][4] = {};

  // --- fp8 section: Gg8 @ W2T8, K = 3072 bytes, BK = 64 ---
  for (int k0 = 0; k0 < 3072; k0 += 64){
    #pragma unroll
    for (int i = 0; i < 2; i++){
      int chunk = i*256 + tid;
      int row = chunk >> 2, c16 = chunk & 3;
      __builtin_amdgcn_global_load_lds(
        (const __attribute__((address_space(1))) void*)&Gg8[(size_t)(m0+row)*3072 + k0 + c16*16],
        (__attribute__((address_space(3))) void*)&As8[(size_t)(i*256 + wave*64)*16], 16, 0, 0);
      __builtin_amdgcn_global_load_lds(
        (const __attribute__((address_space(1))) void*)&W2T8[(size_t)(n0+row)*3072 + k0 + c16*16],
        (__attribute__((address_space(3))) void*)&Bs8[(size_t)(i*256 + wave*64)*16], 16, 0, 0);
    }
    __syncthreads();
    long a8[4][2], b8[4][2];
    #pragma unroll
    for (int i = 0; i < 4; i++){
      int ra = wm*64 + i*16 + l15, rb = wn*64 + i*16 + l15;
      #pragma unroll
      for (int kk = 0; kk < 2; kk++){
        a8[i][kk] = *(const long*)&As8[ra*64 + (((kk*4 + lg) ^ (l15 & 7)) << 3)];
        b8[i][kk] = *(const long*)&Bs8[rb*64 + (((kk*4 + lg) ^ (l15 & 7)) << 3)];
      }
    }
    #pragma unroll
    for (int kk = 0; kk < 2; kk++)
      #pragma unroll
      for (int i = 0; i < 4; i++)
        #pragma unroll
        for (int j = 0; j < 4; j++)
          acc[i][j] = __builtin_amdgcn_mfma_f32_16x16x32_fp8_fp8(a8[i][kk], b8[j][kk], acc[i][j], 0, 0, 0);
    __syncthreads();
  }

  // --- bf16 section: Og @ WoT, K = 768 ---
  for (int k0 = 0; k0 < 768; k0 += 64){
    #pragma unroll
    for (int i = 0; i < 4; i++){
      int chunk = i*256 + tid;
      int row = chunk >> 3, seg = (chunk & 7) ^ (row & 7);
      __builtin_amdgcn_global_load_lds(
        (const __attribute__((address_space(1))) void*)&Og[(size_t)(m0+row)*768 + k0 + seg*8],
        (__attribute__((address_space(3))) void*)&As[(size_t)(i*256 + wave*64)*8], 16, 0, 0);
      __builtin_amdgcn_global_load_lds(
        (const __attribute__((address_space(1))) void*)&WoT[(size_t)(n0+row)*768 + k0 + seg*8],
        (__attribute__((address_space(3))) void*)&Bs[(size_t)(i*256 + wave*64)*8], 16, 0, 0);
    }
    __syncthreads();
    bf16x8 af[4][2], bfr[4][2];
    #pragma unroll
    for (int i = 0; i < 4; i++){
      int ra = wm*64 + i*16 + l15, rb = wn*64 + i*16 + l15;
      #pragma unroll
      for (int kk = 0; kk < 2; kk++){
        af[i][kk]  = *(const bf16x8*)&As[ra*64 + (((kk*4 + lg) ^ (l15 & 7)) << 3)];
        bfr[i][kk] = *(const bf16x8*)&Bs[rb*64 + (((kk*4 + lg) ^ (l15 & 7)) << 3)];
      }
    }
    #pragma unroll
    for (int kk = 0; kk < 2; kk++)
      #pragma unroll
      for (int i = 0; i < 4; i++)
        #pragma unroll
        for (int j = 0; j < 4; j++)
          acc[i][j] = __builtin_amdgcn_mfma_f32_16x16x32_bf16(af[i][kk], bfr[j][kk], acc[i][j], 0, 0, 0);
    __syncthreads();
  }

  #pragma unroll
  for (int i = 0; i < 4; i++){
    int row_base = m0 + wm*64 + i*16 + lg*4;
    #pragma unroll
    for (int j = 0; j < 4; j++){
      int col = n0 + wn*64 + j*16 + l15;
      float bcol = bo2[col];
      #pragma unroll
      for (int r = 0; r < 4; r++){
        size_t idx = (size_t)(row_base + r) * Nn + col;
        Cout[idx] = acc[i][j][r] + bcol + x[idx];
      }
    }
  }
}

// ---------------------------------------------------------------------------
extern "C" void kernel_launch(void* const* d_in, const int* in_sizes, int n_in,
                              void* d_out, int out_size, void* d_ws, size_t ws_size,
                              hipStream_t stream){
  const float* x   = (const float*)d_in[0];
  const float* sp  = (const float*)d_in[1];
  const float* ed  = (const float*)d_in[2];
  const float* Wq  = (const float*)d_in[3];
  const float* Wk  = (const float*)d_in[4];
  const float* Wv  = (const float*)d_in[5];
  const float* bv  = (const float*)d_in[6];
  const float* Wo  = (const float*)d_in[7];
  const float* bo  = (const float*)d_in[8];
  const float* g1  = (const float*)d_in[9];
  const float* be1 = (const float*)d_in[10];
  const float* g2  = (const float*)d_in[11];
  const float* be2 = (const float*)d_in[12];
  const float* W1  = (const float*)d_in[13];
  const float* bf1 = (const float*)d_in[14];
  const float* W2  = (const float*)d_in[15];
  const float* bf2 = (const float*)d_in[16];

  char* w = (char*)d_ws;
  size_t off = 0;
  auto alloc = [&](size_t bytes)->void*{ void* p = w + off; off += (bytes + 255) & ~(size_t)255; return p; };
  u8*    Gg8   = (u8*)   alloc(8192ull*3072);     // 25.2 MB fp8 (pre-swizzled)
  u16*   qkv   = (u16*)  alloc(8192ull*2304*2);   // 37.7 MB
  u16*   VTg   = (u16*)  alloc(8192ull*768*2);
  u16*   hn    = (u16*)  alloc(8192ull*768*2);
  u16*   Og    = (u16*)  alloc(8192ull*768*2);
  u16*   biasPb= (u16*)  alloc(16ull*512*512*2);
  u16*   WqkvT = (u16*)  alloc(2304ull*768*2);
  u16*   WoT   = (u16*)  alloc(768ull*768*2);
  u16*   W1T   = (u16*)  alloc(3072ull*768*2);
  u8*    W2T8  = (u8*)   alloc(768ull*3072);      // 2.4 MB fp8 (pre-swizzled)
  float* qkvb  = (float*)alloc(2304ull*4);
  float* bf1f  = (float*)alloc(3072ull*4);
  float* bo2   = (float*)alloc(768ull*4);

  const float qscale = 0.03608439182435161f * LOG2E;  // D^-0.5 * log2e folded into Wq

  // --- prep: 4 independent jobs, one dispatch ---
  prep_all<<<13152, 256, 0, stream>>>(sp, ed, Wq, Wk, Wv, Wo, W1, W2, g1, g2,
                                      be1, be2, bv, bf1, bo, bf2, x,
                                      biasPb, WqkvT, WoT, W1T, W2T8,
                                      qkvb, bf1f, bo2, hn, qscale);

  // --- qkv projection with fused V-transpose ---
  gemm_qkv<<<dim3(18,64),256,0,stream>>>(hn, WqkvT, qkv, qkvb, VTg);

  // --- attention + FFN1 fused (range-partitioned, T5 setprio) ---
  attn_ffn1<<<2304, 256, 0, stream>>>(qkv, VTg, biasPb, Og, hn, W1T, Gg8, bf1f);

  // --- final: fp8 FFN2 + bf16 o-proj as one GEMM (+bo2 +x) ---
  gemm_fin<<<dim3(6,64),256,0,stream>>>(Gg8, Og, W2T8, WoT, (float*)d_out, bo2, x);
}